// Round 9
// baseline (36.217 us; speedup 1.0000x reference)
//
#include <hip/hip_runtime.h>

#define EMB 200
#define U_DIM 32
#define T_DIM 4
#define DIM_A 32
#define NN 10
#define BLK 512
#define NWAVE 8
#define BPW 8
#define TW_FLOATS (T_DIM * U_DIM * EMB)   // 25600 floats = 102400 B

__device__ __forceinline__ float readlane_f(float v, int l) {
    return __int_as_float(__builtin_amdgcn_readlane(__float_as_int(v), l));
}

__global__ __launch_bounds__(BLK, 2) void gatne_fused(
    const int* __restrict__ train_inputs,
    const int* __restrict__ train_types,
    const int* __restrict__ node_neigh,
    const float* __restrict__ node_emb,
    const float* __restrict__ node_type_emb,
    const float* __restrict__ tw,
    const float* __restrict__ tw1,
    const float* __restrict__ tw2,
    float* __restrict__ out)
{
    __shared__ float s_tw[TW_FLOATS];                            // 102.4 KB
    __shared__ __align__(16) float s_nte[NWAVE][T_DIM][U_DIM];   // 4 KB

    const int wid  = threadIdx.x >> 6;
    const int lane = threadIdx.x & 63;
    const int u    = lane & 31;
    const int th   = lane >> 5;
    const int base = blockIdx.x * (NWAVE * BPW);

    // ---- hoist all index/type loads (24 VGPRs; cap is 256 at BLK=512) ----
    int nb[BPW], ty[BPW], nd[BPW];
    #pragma unroll
    for (int i = 0; i < BPW; ++i) {
        const int b = base + i * NWAVE + wid;
        nb[i] = (lane < T_DIM * NN) ? node_neigh[b * T_DIM * NN + lane] : 0;
        ty[i] = train_types[b];
        nd[i] = train_inputs[b];
    }

    // ---- stage all of tw into LDS (covers index-load latency) ----
    {
        const float4* src = (const float4*)tw;
        float4*       dst = (float4*)s_tw;
        #pragma unroll
        for (int k = 0; k < 13; ++k) {
            const int i = threadIdx.x + k * BLK;
            if (i < TW_FLOATS / 4) dst[i] = src[i];
        }
    }

    // gather staging registers, double-buffered, 2-AHEAD pipeline:
    // at steady state both buffers hold in-flight loads (40 outstanding/wave).
    float g[2][2][NN];
    #pragma unroll
    for (int pb = 0; pb < 2; ++pb) {
        #pragma unroll
        for (int tt = 0; tt < 2; ++tt) {
            #pragma unroll
            for (int n = 0; n < NN; ++n) {
                const int i0 = __builtin_amdgcn_readlane(nb[pb], (2 * tt) * NN + n);
                const int i1 = __builtin_amdgcn_readlane(nb[pb], (2 * tt + 1) * NN + n);
                const int idx = th ? i1 : i0;
                g[pb][tt][n] = node_type_emb[((long)idx * T_DIM + (2 * tt + th)) * U_DIM + u];
            }
        }
    }

    // prefetch b0's node-embedding row
    float4 nv_cur = make_float4(0.f, 0.f, 0.f, 0.f);
    if (lane < EMB / 4)
        nv_cur = *(const float4*)(node_emb + (size_t)nd[0] * EMB + lane * 4);

    __syncthreads();

    #pragma unroll
    for (int i = 0; i < BPW; ++i) {
        const int cb   = i & 1;
        const int b    = base + i * NWAVE + wid;
        const int type = ty[i];

        // consume staged gathers -> s_nte (per-wave slot, no barrier)
        #pragma unroll
        for (int tt = 0; tt < 2; ++tt) {
            float a0 = 0.f;
            #pragma unroll
            for (int n = 0; n < NN; ++n) a0 += g[cb][tt][n];
            s_nte[wid][tt * 2 + th][u] = a0;
        }

        // issue gathers for b_{i+2} into the buffer just freed — 40 loads
        // stay in flight per wave across two full compute windows (T14)
        if (i + 2 < BPW) {
            #pragma unroll
            for (int tt = 0; tt < 2; ++tt) {
                #pragma unroll
                for (int n = 0; n < NN; ++n) {
                    const int i0 = __builtin_amdgcn_readlane(nb[i + 2], (2 * tt) * NN + n);
                    const int i1 = __builtin_amdgcn_readlane(nb[i + 2], (2 * tt + 1) * NN + n);
                    const int idx = th ? i1 : i0;
                    g[cb][tt][n] = node_type_emb[((long)idx * T_DIM + (2 * tt + th)) * U_DIM + u];
                }
            }
        }

        // prefetch next b's node row (consumed next iteration)
        float4 nv_next = make_float4(0.f, 0.f, 0.f, 0.f);
        if (i + 1 < BPW && lane < EMB / 4)
            nv_next = *(const float4*)(node_emb + (size_t)nd[i + 1] * EMB + lane * 4);

        // ---- attention: s_nte via uniform float4 broadcasts ----
        const float* tw1p = tw1 + type * U_DIM * DIM_A;
        const float  w2   = tw2[type * DIM_A + u];
        float sc[2];
        #pragma unroll
        for (int tt = 0; tt < 2; ++tt) {
            const int t = tt * 2 + th;
            float a1 = 0.f;
            #pragma unroll
            for (int q = 0; q < 8; ++q) {
                const float4 bc = *(const float4*)&s_nte[wid][t][q * 4];
                a1 += bc.x * tw1p[(q * 4 + 0) * DIM_A + u];
                a1 += bc.y * tw1p[(q * 4 + 1) * DIM_A + u];
                a1 += bc.z * tw1p[(q * 4 + 2) * DIM_A + u];
                a1 += bc.w * tw1p[(q * 4 + 3) * DIM_A + u];
            }
            float s = tanhf(a1) * w2;
            #pragma unroll
            for (int m = 1; m < 32; m <<= 1) s += __shfl_xor(s, m, 64);
            sc[tt] = s;
        }
        const float o0 = __shfl_xor(sc[0], 32, 64);
        const float o1 = __shfl_xor(sc[1], 32, 64);
        const float s0 = th ? o0    : sc[0];
        const float s1 = th ? sc[0] : o0;
        const float s2 = th ? o1    : sc[1];
        const float s3 = th ? sc[1] : o1;

        const float mx  = fmaxf(fmaxf(s0, s1), fmaxf(s2, s3));
        const float e0  = __expf(s0 - mx), e1 = __expf(s1 - mx);
        const float e2  = __expf(s2 - mx), e3 = __expf(s3 - mx);
        const float inv = 1.f / (e0 + e1 + e2 + e3);
        const float comb = (e0 * s_nte[wid][0][u] + e1 * s_nte[wid][1][u] +
                            e2 * s_nte[wid][2][u] + e3 * s_nte[wid][3][u]) * inv;

        // ---- matvec from LDS-resident tw; comb scalar via readlane ----
        const float* twp = s_tw + type * U_DIM * EMB;
        float4 v = nv_cur;
        if (lane < EMB / 4) {
            #pragma unroll
            for (int uu = 0; uu < U_DIM; ++uu) {
                const float  cg = readlane_f(comb, uu);
                const float4 w  = *(const float4*)(twp + uu * EMB + lane * 4);
                v.x += cg * w.x; v.y += cg * w.y; v.z += cg * w.z; v.w += cg * w.w;
            }
        }
        float ss = (lane < EMB / 4) ? (v.x * v.x + v.y * v.y + v.z * v.z + v.w * v.w) : 0.f;
        #pragma unroll
        for (int m = 1; m < 64; m <<= 1) ss += __shfl_xor(ss, m, 64);
        const float rinv = 1.f / fmaxf(sqrtf(ss), 1e-12f);
        if (lane < EMB / 4) {
            float4 o = make_float4(v.x * rinv, v.y * rinv, v.z * rinv, v.w * rinv);
            *(float4*)(out + (size_t)b * EMB + lane * 4) = o;
        }
        nv_cur = nv_next;
    }
}

extern "C" void kernel_launch(void* const* d_in, const int* in_sizes, int n_in,
                              void* d_out, int out_size, void* d_ws, size_t ws_size,
                              hipStream_t stream) {
    const int*   train_inputs = (const int*)d_in[0];
    const int*   train_types  = (const int*)d_in[1];
    const int*   node_neigh   = (const int*)d_in[2];
    const float* node_emb     = (const float*)d_in[3];
    const float* node_type_e  = (const float*)d_in[4];
    const float* tw           = (const float*)d_in[5];
    const float* tw1          = (const float*)d_in[6];
    const float* tw2          = (const float*)d_in[7];
    float*       out          = (float*)d_out;

    const int B = in_sizes[0];                 // 16384
    const int blocks = B / (NWAVE * BPW);      // 256 — one block per CU

    gatne_fused<<<blocks, BLK, 0, stream>>>(
        train_inputs, train_types, node_neigh,
        node_emb, node_type_e, tw, tw1, tw2, out);
}